// Round 2
// baseline (778.942 us; speedup 1.0000x reference)
//
#include <hip/hip_runtime.h>

// FamilyMLPLinear: per-class MLP (16 -> 4 -> 1) over [B=512, C=17929], fp32.
// HBM-bound: x (587 MB) streamed once, out (37 MB) written once.
// v2: 4 classes/thread with float4 (align-4) x loads; W1 staged in LDS with
// conflict-free transposed rows (stride 68 floats == 4 dwords mod 32);
// b1/W2/b2 per-thread in registers.

#define NM 16      // models (input dim)
#define NH 4       // hidden
#define NB 512     // batch
#define NC 17929   // classes
#define CBK 256    // classes per block
#define ROWS 68    // LDS row stride in floats (68 % 8 == 4 -> conflict-free b128)
#define GY 16      // b-slices in grid.y
#define BPB (NB / GY)  // 32 batches per block

typedef float f4 __attribute__((ext_vector_type(4)));

__device__ __forceinline__ f4 load4(const float* p) {
    f4 r; __builtin_memcpy(&r, p, 16); return r;   // align-4 dwordx4, legal on gfx950
}
__device__ __forceinline__ void store4(float* p, f4 v) {
    __builtin_memcpy(p, &v, 16);
}

__global__ __launch_bounds__(256) void FamilyMLPLinear_kernel(
    const float* __restrict__ x,    // [M, B, C]
    const float* __restrict__ W1,   // [C, H, M]
    const float* __restrict__ b1,   // [C, H]
    const float* __restrict__ W2,   // [C, H]
    const float* __restrict__ b2,   // [C]
    float* __restrict__ out)        // [B, C]
{
    __shared__ float w1s[CBK * ROWS];   // 69632 B -> 2 blocks/CU

    const int tid = threadIdx.x;
    const int cb  = blockIdx.x * CBK;

    // ---- stage W1 for classes [cb, cb+CBK) into LDS ----
    // flat float4 index f in block region: class i = f>>4, chunk kk = f&15
    // storage row r(i) = (i>>2) + (i&3)*64  (so compute lane l=q reads row q+64*cls,
    // lane stride 68 dwords == 4 mod 32 -> conflict-free ds_read_b128)
    {
        const float* src = W1 + (size_t)cb * (NH * NM);
        const int nclass = min(CBK, NC - cb);
        #pragma unroll
        for (int k = 0; k < 16; ++k) {
            const int f  = tid + 256 * k;
            const int i  = f >> 4;
            const int kk = f & 15;
            if (i < nclass) {
                f4 v = load4(src + (size_t)i * (NH * NM) + 4 * kk);
                const int r = (i >> 2) + (i & 3) * 64;
                *(f4*)&w1s[r * ROWS + 4 * kk] = v;
            }
        }
    }

    // ---- per-thread small weights in registers (4 fixed classes) ----
    const int q  = tid & 63;    // class-quad lane
    const int bs = tid >> 6;    // batch sub-lane (0..3)
    const int lc = q << 2;
    const int cq = cb + lc;     // first class of this thread's quad

    f4 b1v[4], w2v[4];
    float b2v[4];
    #pragma unroll
    for (int cls = 0; cls < 4; ++cls) {
        const int c = cq + cls;
        if (c < NC) {
            b1v[cls] = load4(b1 + (size_t)c * NH);
            w2v[cls] = load4(W2 + (size_t)c * NH);
            b2v[cls] = b2[c];
        } else {
            f4 z = {0.f, 0.f, 0.f, 0.f};
            b1v[cls] = z; w2v[cls] = z; b2v[cls] = 0.f;
        }
    }

    __syncthreads();

    const bool fullquad = (cq + 3 < NC);
    const int b_base = blockIdx.y * BPB + bs;
    const size_t MS = (size_t)NB * NC;   // m-stride in x

    #pragma unroll 1
    for (int it = 0; it < BPB / 4; ++it) {
        const int b = b_base + 4 * it;

        if (fullquad) {
            // 16 independent float4 x loads (16 B/lane, coalesced per wave)
            f4 xq[NM];
            const float* xb = x + (size_t)b * NC + cq;
            #pragma unroll
            for (int m = 0; m < NM; ++m)
                xq[m] = load4(xb + (size_t)m * MS);

            f4 accv;
            #pragma unroll
            for (int cls = 0; cls < 4; ++cls) {
                const f4* wrow = (const f4*)&w1s[(q + (cls << 6)) * ROWS];
                float acc = b2v[cls];
                #pragma unroll
                for (int j = 0; j < NH; ++j) {
                    float h = b1v[cls][j];
                    #pragma unroll
                    for (int t = 0; t < 4; ++t) {
                        f4 w = wrow[j * 4 + t];   // W1[c][j][4t..4t+3]
                        h = fmaf(xq[4 * t + 0][cls], w[0], h);
                        h = fmaf(xq[4 * t + 1][cls], w[1], h);
                        h = fmaf(xq[4 * t + 2][cls], w[2], h);
                        h = fmaf(xq[4 * t + 3][cls], w[3], h);
                    }
                    h = fmaxf(h, 0.f);
                    acc = fmaf(h, w2v[cls][j], acc);
                }
                accv[cls] = acc;
            }
            store4(out + (size_t)b * NC + cq, accv);
        } else {
            // tail quad (at most the last few classes): scalar path
            #pragma unroll
            for (int cls = 0; cls < 4; ++cls) {
                const int c = cq + cls;
                if (c >= NC) break;
                const float* xb = x + (size_t)b * NC + c;
                float xv[NM];
                #pragma unroll
                for (int m = 0; m < NM; ++m)
                    xv[m] = xb[(size_t)m * MS];
                const float* wrow = &w1s[(q + (cls << 6)) * ROWS];
                float acc = b2v[cls];
                #pragma unroll
                for (int j = 0; j < NH; ++j) {
                    float h = b1v[cls][j];
                    #pragma unroll
                    for (int m = 0; m < NM; ++m)
                        h = fmaf(xv[m], wrow[j * NM + m], h);
                    h = fmaxf(h, 0.f);
                    acc = fmaf(h, w2v[cls][j], acc);
                }
                out[(size_t)b * NC + c] = acc;
            }
        }
    }
}

extern "C" void kernel_launch(void* const* d_in, const int* in_sizes, int n_in,
                              void* d_out, int out_size, void* d_ws, size_t ws_size,
                              hipStream_t stream) {
    const float* x  = (const float*)d_in[0];
    const float* W1 = (const float*)d_in[1];
    const float* b1 = (const float*)d_in[2];
    const float* W2 = (const float*)d_in[3];
    const float* b2 = (const float*)d_in[4];
    float* out = (float*)d_out;

    dim3 grid((NC + CBK - 1) / CBK, GY);   // 71 x 16
    FamilyMLPLinear_kernel<<<grid, 256, 0, stream>>>(x, W1, b1, W2, b2, out);
}